// Round 1
// 2053.342 us; speedup vs baseline: 1.0594x; 1.0594x over previous
//
#include <hip/hip_runtime.h>

#define N_ROWS 65536
#define DIM    2048
#define EMBD   256
#define NEXP   64
#define BMAIN  64
#define EPSN   1e-12f
#define TAU    5e-4f
#define CAP    8192
#define RPB    4

// ws layout (bytes): flag counter+list | emb col inv-norms | W frag-pack | emb_n frag-pack
#define WS_EINV   65536
#define WS_WPACK  131072              // 2 limbs x 65536 frags x 16B = 2 MiB
#define WS_EPACK  (131072 + 2097152) // 2 limbs x 2048 frags x 16B = 64 KiB

typedef short short8 __attribute__((ext_vector_type(8)));
typedef float f32x4 __attribute__((ext_vector_type(4)));
typedef unsigned short ushort_t;

__device__ __forceinline__ ushort_t f2bf(float v) {
  unsigned u = __float_as_uint(v);
  u += 0x7fffu + ((u >> 16) & 1u);   // RNE
  return (ushort_t)(u >> 16);
}
__device__ __forceinline__ float bf2f(ushort_t h) {
  return __uint_as_float((unsigned)h << 16);
}

__device__ __forceinline__ void cvt8(const float4 a, const float4 b,
                                     short8& hv, short8& lv) {
  float v[8] = {a.x, a.y, a.z, a.w, b.x, b.y, b.z, b.w};
  #pragma unroll
  for (int j = 0; j < 8; ++j) {
    ushort_t h = f2bf(v[j]);
    hv[j] = (short)h;
    lv[j] = (short)f2bf(v[j] - bf2f(h));
  }
}

__device__ __forceinline__ void top3_insert(float w, int j,
                                            float& v1, int& i1,
                                            float& v2, int& i2,
                                            float& v3, int& i3) {
  bool b1 = (w > v1) || (w == v1 && j < i1);
  bool b2 = (w > v2) || (w == v2 && j < i2);
  bool b3 = (w > v3) || (w == v3 && j < i3);
  if (b1)      { v3 = v2; i3 = i2; v2 = v1; i2 = i1; v1 = w; i1 = j; }
  else if (b2) { v3 = v2; i3 = i2; v2 = w;  i2 = j; }
  else if (b3) { v3 = w;  i3 = j; }
}

__device__ __forceinline__ void top2_insert_d(double w, int j,
                                              double& v1, int& i1,
                                              double& v2, int& i2) {
  bool b1 = (w > v1) || (w == v1 && j < i1);
  bool b2 = (w > v2) || (w == v2 && j < i2);
  if (b1) { v2 = v1; i2 = i1; v1 = w; i1 = j; }
  else if (b2) { v2 = w; i2 = j; }
}

// ---------------- prep 1: expert-embedding column inverse norms ----------------
__global__ __launch_bounds__(256)
void prep_norms(const float* __restrict__ emb, char* __restrict__ ws) {
  __shared__ float part[4][64];
  const int tid = threadIdx.x;
  const int e = tid & 63, p = tid >> 6;
  float s = 0.f;
  for (int m = p * 64; m < p * 64 + 64; ++m) {
    float v = emb[m * NEXP + e];
    s += v * v;
  }
  part[p][e] = s;
  __syncthreads();
  if (tid < 64) {
    float* einv = (float*)(ws + WS_EINV);
    einv[tid] = 1.0f / sqrtf(part[0][tid] + part[1][tid] + part[2][tid] +
                             part[3][tid] + EPSN);
  }
}

// ---------------- prep 2: pack W and emb_n into MFMA B-fragment order ----------
// B-frag (16x16x32): lane l holds B[k = 32*s + (l>>4)*8 + j][n = 16*t + (l&15)]
__global__ __launch_bounds__(256)
void prep_pack(const float* __restrict__ Wp, const float* __restrict__ emb,
               char* __restrict__ ws) {
  const int gid = blockIdx.x * 256 + threadIdx.x;
  if (blockIdx.x < 256) {
    short8* wH = (short8*)(ws + WS_WPACK);
    short8* wL = wH + 65536;
    const int l = gid & 63, s = (gid >> 6) & 63, t = gid >> 12;
    short8 hv, lv;
    #pragma unroll
    for (int j = 0; j < 8; ++j) {
      float v = Wp[(size_t)(32 * s + ((l >> 4) << 3) + j) * EMBD + 16 * t + (l & 15)];
      ushort_t h = f2bf(v);
      hv[j] = (short)h;
      lv[j] = (short)f2bf(v - bf2f(h));
    }
    wH[(t * 64 + s) * 64 + l] = hv;
    wL[(t * 64 + s) * 64 + l] = lv;
  } else {
    const int g2 = gid - 65536;
    const int l = g2 & 63, s2 = (g2 >> 6) & 7, nt = g2 >> 9;
    const float* einv = (const float*)(ws + WS_EINV);
    short8* eH = (short8*)(ws + WS_EPACK);
    short8* eL = eH + 2048;
    short8 hv, lv;
    #pragma unroll
    for (int j = 0; j < 8; ++j) {
      int k = 32 * s2 + ((l >> 4) << 3) + j;
      int n = 16 * nt + (l & 15);
      float v = emb[k * NEXP + n] * einv[n];
      ushort_t h = f2bf(v);
      hv[j] = (short)h;
      lv[j] = (short)f2bf(v - bf2f(h));
    }
    eH[(nt * 8 + s2) * 64 + l] = hv;
    eL[(nt * 8 + s2) * 64 + l] = lv;
  }
}

// ---------------- main: 64-row tile, bf16 2-limb MFMA GEMM + fused gating ------
// A-staging slot swizzle: kills the 4-way LDS write bank conflict while keeping
// both write and read sides bank-quad-distinct within every 8-lane group.
__device__ __forceinline__ int aswz(int idx) {
  return idx ^ (((idx >> 4) & 3) << 1);
}

__global__ __launch_bounds__(256, 3)
void gate_main(const float* __restrict__ x, const float* __restrict__ temp,
               float* __restrict__ out, char* __restrict__ ws) {
  // A staging (double-buffered, frag-packed) & cos buffer union + P pack + norms
  __shared__ alignas(16) union {
    struct { ushort_t AH[2][4][64][8]; ushort_t AL[2][4][64][8]; } a;  // [buf][mt][slot][j]
    float cb[32][68];
  } u;
  __shared__ ushort_t PH[2][8][64][8];  // 16 KiB  [mt2][s2][lane][j]
  __shared__ ushort_t PL[2][8][64][8];  // 16 KiB
  __shared__ float sPart[4][64];
  __shared__ float sInv[64];

  const int tid  = threadIdx.x;
  const int lane = tid & 63;
  const int w    = tid >> 6;
  const int lm   = lane & 15;
  const int lq   = lane >> 4;
  const int n0   = blockIdx.x * BMAIN;

  const short8* wH = (const short8*)(ws + WS_WPACK);
  const short8* wL = wH + 65536;
  const short8* eH = (const short8*)(ws + WS_EPACK);
  const short8* eL = eH + 2048;
  int* flag = (int*)ws;

  f32x4 acc[4][4];
  #pragma unroll
  for (int i = 0; i < 4; ++i)
    #pragma unroll
    for (int j = 0; j < 4; ++j) acc[i][j] = (f32x4){0.f, 0.f, 0.f, 0.f};

  const int arow = tid >> 2;   // 0..63
  const int achk = tid & 3;    // k-chunk 0..3 (8 floats each)
  const float4* xld = (const float4*)(x + (size_t)(n0 + arow) * DIM + achk * 8);
  const int mtW   = arow >> 4;
  const int slotW = aswz((arow & 15) + 16 * achk);
  const int slotR = aswz(lane);

  // prologue: stage s = 0 into buffer 0
  {
    float4 xa = xld[0];
    float4 xb = xld[1];
    short8 hv, lv;
    cvt8(xa, xb, hv, lv);
    *(short8*)&u.a.AH[0][mtW][slotW][0] = hv;
    *(short8*)&u.a.AL[0][mtW][slotW][0] = lv;
  }
  __syncthreads();

  for (int s = 0; s < 64; ++s) {
    const int cur = s & 1;
    // issue next x-tile loads early: latency hides under B loads + MFMAs
    const int sn = (s < 63) ? s + 1 : 63;
    float4 nxa = xld[8 * sn];
    float4 nxb = xld[8 * sn + 1];

    // A fragments (both limbs) from current buffer
    short8 AfH[4], AfL[4];
    #pragma unroll
    for (int mt = 0; mt < 4; ++mt) {
      AfH[mt] = *(const short8*)&u.a.AH[cur][mt][slotR][0];
      AfL[mt] = *(const short8*)&u.a.AL[cur][mt][slotR][0];
    }

    // B fragments pipelined per nt (16 live B VGPRs instead of 32)
    short8 Bh = wH[((4 * w) * 64 + s) * 64 + lane];
    short8 Bl = wL[((4 * w) * 64 + s) * 64 + lane];
    __builtin_amdgcn_s_setprio(1);
    #pragma unroll
    for (int nt = 0; nt < 4; ++nt) {
      short8 Bh2, Bl2;
      if (nt < 3) {
        Bh2 = wH[((4 * w + nt + 1) * 64 + s) * 64 + lane];
        Bl2 = wL[((4 * w + nt + 1) * 64 + s) * 64 + lane];
      }
      // per-acc order identical to previous verified kernel: AH*BH, AH*BL, AL*BH
      #pragma unroll
      for (int mt = 0; mt < 4; ++mt) {
        acc[mt][nt] = __builtin_amdgcn_mfma_f32_16x16x32_bf16(AfH[mt], Bh, acc[mt][nt], 0, 0, 0);
        acc[mt][nt] = __builtin_amdgcn_mfma_f32_16x16x32_bf16(AfH[mt], Bl, acc[mt][nt], 0, 0, 0);
        acc[mt][nt] = __builtin_amdgcn_mfma_f32_16x16x32_bf16(AfL[mt], Bh, acc[mt][nt], 0, 0, 0);
      }
      Bh = Bh2; Bl = Bl2;
    }
    __builtin_amdgcn_s_setprio(0);

    // convert the prefetched x-tile and stage into the other buffer
    if (s < 63) {
      short8 hv, lv;
      cvt8(nxa, nxb, hv, lv);
      *(short8*)&u.a.AH[cur ^ 1][mtW][slotW][0] = hv;
      *(short8*)&u.a.AL[cur ^ 1][mtW][slotW][0] = lv;
    }
    __syncthreads();   // single barrier per K-step (double-buffered staging)
  }

  // ---- row inverse L2 norms (row = mt*16 + lq*4 + reg, col = w*64 + nt*16 + lm)
  #pragma unroll
  for (int mt = 0; mt < 4; ++mt) {
    #pragma unroll
    for (int reg = 0; reg < 4; ++reg) {
      float ssum = 0.f;
      #pragma unroll
      for (int nt = 0; nt < 4; ++nt) {
        float v = acc[mt][nt][reg];
        ssum += v * v;
      }
      #pragma unroll
      for (int off = 1; off < 16; off <<= 1) ssum += __shfl_xor(ssum, off, 16);
      if (lm == 0) sPart[w][mt * 16 + lq * 4 + reg] = ssum;
    }
  }
  __syncthreads();
  if (tid < 64)
    sInv[tid] = 1.0f / sqrtf(sPart[0][tid] + sPart[1][tid] + sPart[2][tid] +
                             sPart[3][tid] + EPSN);
  __syncthreads();

  const float T = temp[0];
  float* o_w   = out;
  float* o_idx = out + (size_t)N_ROWS * 64;
  float* o_lg  = o_idx + (size_t)N_ROWS * 2;
  float* o_cos = o_lg + (size_t)N_ROWS * 64;
  float* o_rp  = o_cos + (size_t)N_ROWS * 64;

  for (int h = 0; h < 2; ++h) {
    // pack normalized P limbs for rows 32h..32h+31 into A-frag order
    #pragma unroll
    for (int mt = 2 * h; mt < 2 * h + 2; ++mt) {
      #pragma unroll
      for (int nt = 0; nt < 4; ++nt) {
        #pragma unroll
        for (int reg = 0; reg < 4; ++reg) {
          const int row = mt * 16 + lq * 4 + reg;
          const int col = w * 64 + nt * 16 + lm;      // EMB index (GEMM2 K)
          float p = acc[mt][nt][reg] * sInv[row];
          ushort_t hi = f2bf(p);
          ushort_t lo = f2bf(p - bf2f(hi));
          const int rr = row - 32 * h;
          const int li = (rr & 15) + 16 * ((col >> 3) & 3);
          PH[rr >> 4][col >> 5][li][col & 7] = hi;
          PL[rr >> 4][col >> 5][li][col & 7] = lo;
        }
      }
    }
    __syncthreads();
    // GEMM2: cos[32 x 64] = P_n @ emb_n ; wave w -> expert cols 16w..16w+15
    f32x4 a2[2];
    a2[0] = (f32x4){0.f, 0.f, 0.f, 0.f};
    a2[1] = (f32x4){0.f, 0.f, 0.f, 0.f};
    for (int s2 = 0; s2 < 8; ++s2) {
      short8 bh = eH[(w * 8 + s2) * 64 + lane];
      short8 bl = eL[(w * 8 + s2) * 64 + lane];
      #pragma unroll
      for (int m2 = 0; m2 < 2; ++m2) {
        short8 ph = *(const short8*)&PH[m2][s2][lane][0];
        short8 pl = *(const short8*)&PL[m2][s2][lane][0];
        a2[m2] = __builtin_amdgcn_mfma_f32_16x16x32_bf16(ph, bh, a2[m2], 0, 0, 0);
        a2[m2] = __builtin_amdgcn_mfma_f32_16x16x32_bf16(ph, bl, a2[m2], 0, 0, 0);
        a2[m2] = __builtin_amdgcn_mfma_f32_16x16x32_bf16(pl, bh, a2[m2], 0, 0, 0);
      }
    }
    // stage cos into LDS (reuses A-staging union)
    #pragma unroll
    for (int m2 = 0; m2 < 2; ++m2)
      #pragma unroll
      for (int reg = 0; reg < 4; ++reg)
        u.cb[m2 * 16 + lq * 4 + reg][w * 16 + lm] = a2[m2][reg];
    __syncthreads();

    if (tid < 128) {
      const int r  = tid >> 2;   // row within half
      const int qq = tid & 3;    // expert quarter
      float cs[16], lg[16];
      #pragma unroll
      for (int i = 0; i < 4; ++i) {
        float4 cv = *(const float4*)&u.cb[r][16 * qq + 4 * i];
        cs[4*i+0] = cv.x; cs[4*i+1] = cv.y; cs[4*i+2] = cv.z; cs[4*i+3] = cv.w;
      }
      #pragma unroll
      for (int j = 0; j < 16; ++j) lg[j] = cs[j] * T;
      float v1 = -3e38f, v2 = -3e38f, v3 = -3e38f;
      int   i1 = 1 << 30, i2 = 1 << 30, i3 = 1 << 30;
      #pragma unroll
      for (int j = 0; j < 16; ++j)
        top3_insert(lg[j], 16 * qq + j, v1, i1, v2, i2, v3, i3);
      #pragma unroll
      for (int off = 1; off < 4; off <<= 1) {
        float w1 = __shfl_xor(v1, off, 4); int j1 = __shfl_xor(i1, off, 4);
        float w2 = __shfl_xor(v2, off, 4); int j2 = __shfl_xor(i2, off, 4);
        float w3 = __shfl_xor(v3, off, 4); int j3 = __shfl_xor(i3, off, 4);
        top3_insert(w1, j1, v1, i1, v2, i2, v3, i3);
        top3_insert(w2, j2, v1, i1, v2, i2, v3, i3);
        top3_insert(w3, j3, v1, i1, v2, i2, v3, i3);
      }
      float ex[16], ssum = 0.f;
      #pragma unroll
      for (int j = 0; j < 16; ++j) { ex[j] = expf(lg[j] - v1); ssum += ex[j]; }
      #pragma unroll
      for (int off = 1; off < 4; off <<= 1) ssum += __shfl_xor(ssum, off, 4);

      const int n = n0 + 32 * h + r;
      const float e21 = expf(v2 - v1);
      const float dm  = 1.0f / (1.0f + e21);
      const size_t ob = (size_t)n * 64 + 16 * qq;
      #pragma unroll
      for (int i = 0; i < 4; ++i) {
        float t4[4], r4[4];
        #pragma unroll
        for (int jj = 0; jj < 4; ++jj) {
          int e = 16 * qq + 4 * i + jj;
          t4[jj] = (e == i1) ? dm : ((e == i2) ? e21 * dm : 0.f);
          r4[jj] = ex[4 * i + jj] / ssum;
        }
        *(float4*)&o_w[ob + 4 * i]   = make_float4(t4[0], t4[1], t4[2], t4[3]);
        *(float4*)&o_rp[ob + 4 * i]  = make_float4(r4[0], r4[1], r4[2], r4[3]);
        *(float4*)&o_lg[ob + 4 * i]  = make_float4(lg[4*i], lg[4*i+1], lg[4*i+2], lg[4*i+3]);
        *(float4*)&o_cos[ob + 4 * i] = make_float4(cs[4*i], cs[4*i+1], cs[4*i+2], cs[4*i+3]);
      }
      if (qq == 0) {
        o_idx[(size_t)n * 2]     = (float)i1;
        o_idx[(size_t)n * 2 + 1] = (float)i2;
        if ((v1 - v2 < TAU) || (v2 - v3 < TAU)) {
          int slot = atomicAdd(&flag[0], 1);
          if (slot < CAP) flag[4 + slot] = n;
        }
      }
    }
    __syncthreads();
  }
}

// ---------------- fp64 refinement of near-tie rows ----------------------------
// Same flagged set, same fp64 math; projection loop vectorized, cosine phase
// parallelized across all 256 threads (4 x 64-element partials + LDS combine).
__global__ __launch_bounds__(256)
void refine_kernel(const float* __restrict__ x,
                   const float* __restrict__ Wp,
                   const float* __restrict__ emb,
                   const float* __restrict__ temp,
                   float* __restrict__ out,
                   const int* __restrict__ ws) {
  __shared__ float  xs[RPB][DIM];
  __shared__ double projd[RPB][EMBD];
  __shared__ double embinv[NEXP];
  __shared__ double red[256];

  const int tid = threadIdx.x;
  int cnt = ws[0];
  if (cnt > CAP) cnt = CAP;
  const int base = blockIdx.x * RPB;
  if (base >= cnt) return;
  const int nr = min(RPB, cnt - base);
  int rows[RPB];
  #pragma unroll
  for (int j = 0; j < RPB; ++j) rows[j] = ws[4 + base + (j < nr ? j : 0)];

  {
    const int e = tid & 63, part = tid >> 6;
    double s = 0.0;
    for (int m = part * 64; m < part * 64 + 64; ++m) {
      double v = (double)emb[m * NEXP + e];
      s += v * v;
    }
    red[tid] = s;
  }
  __syncthreads();
  if (tid < 64)
    embinv[tid] = 1.0 / sqrt(red[tid] + red[tid + 64] + red[tid + 128] +
                             red[tid + 192] + 1e-12);

  for (int j = 0; j < nr; ++j)
    for (int k = tid * 4; k < DIM; k += 1024)
      *(float4*)&xs[j][k] = *(const float4*)&x[(size_t)rows[j] * DIM + k];
  __syncthreads();

  {
    double s[RPB];
    #pragma unroll
    for (int j = 0; j < RPB; ++j) s[j] = 0.0;
    #pragma unroll 2
    for (int k = 0; k < DIM; k += 4) {
      double w0 = (double)Wp[(size_t)(k + 0) * EMBD + tid];
      double w1 = (double)Wp[(size_t)(k + 1) * EMBD + tid];
      double w2 = (double)Wp[(size_t)(k + 2) * EMBD + tid];
      double w3 = (double)Wp[(size_t)(k + 3) * EMBD + tid];
      #pragma unroll
      for (int j = 0; j < RPB; ++j) {
        float4 xv = *(const float4*)&xs[j][k];
        s[j] += (double)xv.x * w0;
        s[j] += (double)xv.y * w1;
        s[j] += (double)xv.z * w2;
        s[j] += (double)xv.w * w3;
      }
    }
    #pragma unroll
    for (int j = 0; j < RPB; ++j) projd[j][tid] = s[j];
  }
  __syncthreads();

  float* o_w   = out;
  float* o_idx = out + (size_t)N_ROWS * 64;
  float* o_lg  = o_idx + (size_t)N_ROWS * 2;
  float* o_cos = o_lg + (size_t)N_ROWS * 64;
  float* o_rp  = o_cos + (size_t)N_ROWS * 64;
  const double T = (double)temp[0];
  const int e  = tid & 63;
  const int pp = tid >> 6;

  for (int j = 0; j < nr; ++j) {
    // 4-way parallel partial dot: partition pp covers m in [64*pp, 64*pp+64)
    double c0 = 0.0, c1 = 0.0;
    for (int m = 64 * pp; m < 64 * pp + 64; m += 2) {
      c0 += projd[j][m]     * (double)emb[m * NEXP + e];
      c1 += projd[j][m + 1] * (double)emb[(m + 1) * NEXP + e];
    }
    red[tid] = c0 + c1;
    __syncthreads();

    if (tid < 64) {
      const int row = rows[j];
      double c = red[e] + red[e + 64] + red[e + 128] + red[e + 192];
      double q = 0.0;
      #pragma unroll
      for (int p = 0; p < 4; ++p) {
        double v = projd[j][e + 64 * p];
        q += v * v;
      }
      #pragma unroll
      for (int off = 1; off < 64; off <<= 1) q += __shfl_xor(q, off, 64);
      const double invn = 1.0 / sqrt(q + 1e-12);
      c *= invn * embinv[e];
      const double lg = c * T;

      double v1 = lg, v2 = -1.0e300;
      int   i1 = e,  i2 = 1 << 30;
      #pragma unroll
      for (int off = 1; off < 64; off <<= 1) {
        double w1 = __shfl_xor(v1, off, 64); int j1 = __shfl_xor(i1, off, 64);
        double w2 = __shfl_xor(v2, off, 64); int j2 = __shfl_xor(i2, off, 64);
        top2_insert_d(w1, j1, v1, i1, v2, i2);
        top2_insert_d(w2, j2, v1, i1, v2, i2);
      }
      const double ex = exp(lg - v1);
      double ssum = ex;
      #pragma unroll
      for (int off = 1; off < 64; off <<= 1) ssum += __shfl_xor(ssum, off, 64);
      const double e21 = exp(v2 - v1);
      const double dm  = 1.0 / (1.0 + e21);

      const size_t ob = (size_t)row * 64 + e;
      o_w[ob]   = (e == i1) ? (float)dm : ((e == i2) ? (float)(e21 * dm) : 0.0f);
      o_lg[ob]  = (float)lg;
      o_cos[ob] = (float)c;
      o_rp[ob]  = (float)(ex / ssum);
      if (e == 0) {
        o_idx[(size_t)row * 2]     = (float)i1;
        o_idx[(size_t)row * 2 + 1] = (float)i2;
      }
    }
    __syncthreads();
  }
}

extern "C" void kernel_launch(void* const* d_in, const int* in_sizes, int n_in,
                              void* d_out, int out_size, void* d_ws, size_t ws_size,
                              hipStream_t stream) {
  const float* x    = (const float*)d_in[0];
  const float* Wp   = (const float*)d_in[1];
  const float* emb  = (const float*)d_in[2];
  const float* temp = (const float*)d_in[3];
  float* out = (float*)d_out;
  char* ws = (char*)d_ws;
  (void)in_sizes; (void)n_in; (void)out_size; (void)ws_size;

  hipMemsetAsync(d_ws, 0, 64, stream);  // zero flagged-row counter
  prep_norms<<<dim3(1), dim3(256), 0, stream>>>(emb, ws);
  prep_pack<<<dim3(264), dim3(256), 0, stream>>>(Wp, emb, ws);
  gate_main<<<dim3(N_ROWS / BMAIN), dim3(256), 0, stream>>>(x, temp, out, ws);
  refine_kernel<<<dim3(CAP / RPB), dim3(256), 0, stream>>>(
      x, Wp, emb, temp, out, (const int*)ws);
}